// Round 7
// baseline (57.915 us; speedup 1.0000x reference)
//
#include <hip/hip_runtime.h>
#include <hip/hip_bf16.h>
#include <math.h>

#define BATCH 4096
#define FEAT 128
#define C_TOTAL 16384
#define OUT_TYPES 512

typedef short bf16x8 __attribute__((ext_vector_type(8)));
typedef float f32x4 __attribute__((ext_vector_type(4)));
typedef unsigned short u16;

static __device__ __forceinline__ u16 f2bf(float f) {
    __hip_bfloat16 h = __float2bfloat16(f);
    return reinterpret_cast<u16&>(h);
}

// ---------------- prologue: out=bias bcast | centres prep | x prep -----------
__global__ void prologue_kernel(const float* __restrict__ x, const float* __restrict__ centres,
                                const float* __restrict__ ls, const float* __restrict__ bias,
                                u16* __restrict__ xb, u16* __restrict__ cbb,
                                float* __restrict__ cc, float* __restrict__ scale,
                                float* __restrict__ hc, float* __restrict__ xx,
                                float* __restrict__ out) {
    const int b = blockIdx.x;
    const int t = threadIdx.x;
    if (b < 2048) {                       // out[m][n] = bias[n], 8 MB
        int i = b * 256 + t;              // float4 index
        float4 bv = reinterpret_cast<const float4*>(bias)[i & 127];
        reinterpret_cast<float4*>(out)[i] = bv;
        return;
    }
    const bool is_c = (b < 2048 + 256);
    const int row = (is_c ? (b - 2048) : (b - 2304)) * 64 + (t >> 2);
    const int l4 = t & 3;
    const float* src = is_c ? centres : x;
    u16* dstb = is_c ? cbb : xb;
    const float4* p = reinterpret_cast<const float4*>(src + (size_t)row * FEAT);
    ushort4* q = reinterpret_cast<ushort4*>(dstb + (size_t)row * FEAT);
    float s = 0.f;
#pragma unroll
    for (int i = 0; i < 8; ++i) {
        float4 v = p[i * 4 + l4];
        s += v.x * v.x + v.y * v.y + v.z * v.z + v.w * v.w;
        ushort4 h;
        h.x = f2bf(v.x); h.y = f2bf(v.y); h.z = f2bf(v.z); h.w = f2bf(v.w);
        q[i * 4 + l4] = h;
    }
    s += __shfl_xor(s, 1);
    s += __shfl_xor(s, 2);
    if (l4 == 0) {
        if (is_c) {
            cc[row] = s;
            scale[row] = __expf(2.f * ls[row]);
            // exact fire condition: sqd*scale < 96 <=> d - 0.5*xx > 0.5*cc - 48/scale
            hc[row] = 0.5f * s - 48.f * __expf(-2.f * ls[row]);
        } else {
            xx[row] = s;
        }
    }
}

// ---------------- rbf: barrier-free, LDS-free, A-in-regs MFMA ----------------
// 256 thr / 4 independent waves; 2 blocks/CU. Wave: 128 rows x 256 centres
// (16 iters x 16 cols). A (128x128 bf16) in 32 VGPRs; B frags loaded
// global->register (L2-resident cb), 3-deep rotation for 2-iter load lead.
// Screen: acc initialized to -0.5*min(xx) of its 4-row group, so the per-iter
// check is one 32-wide max-tree vs hc (sound superset of tt<96). Rare hits
// recorded in a bitmask; cold post-loop recheck recomputes the tile exactly
// and applies phi + rank-1 atomic update. Hot loop: zero calls, zero barriers.
#define BM 128
#define WN 16                     /* centres per wave-iter */
#define NIT 16                    /* iters per wave */
#define WCHUNK (WN * NIT)         /* 256 centres per wave */
#define CSPLIT 16                 /* 16 chunks of 1024 centres (4 waves) */

__global__ __launch_bounds__(256, 2)
void rbf_kernel(const u16* __restrict__ xb, const u16* __restrict__ cb,
                const float* __restrict__ hc, const float* __restrict__ cc,
                const float* __restrict__ scale, const int* __restrict__ node_id,
                const float* __restrict__ xx, const float* __restrict__ W,
                float* __restrict__ out) {
    const int t = threadIdx.x;
    const int lane = t & 63;
    const int w = t >> 6;                 // wave 0..3
    const int q = lane >> 4;              // k-slice group 0..3
    const int r = lane & 15;
    // bijective XCD remap (512 = 8 XCD x 64): each XCD covers 2 centre-chunks
    const int bid = blockIdx.x;
    const int nid = (bid & 7) * 64 + (bid >> 3);
    const int row0 = (nid & 31) * BM;
    const int cw0 = (nid >> 5) * (CSPLIT == 16 ? 1024 : 1024) + w * WCHUNK;

    // ---- setup: A frags (rows row0+m*16+r, k = q*8 + ks*32) ----
    bf16x8 af[8][4];
#pragma unroll
    for (int m = 0; m < 8; ++m) {
        const u16* xrow = xb + (size_t)(row0 + m * 16 + r) * FEAT + q * 8;
#pragma unroll
        for (int ks = 0; ks < 4; ++ks)
            af[m][ks] = *reinterpret_cast<const bf16x8*>(xrow + ks * 32);
    }
    // negated half-min of xx over each 4-row group this lane owns (acc bias)
    float nxh[8];
#pragma unroll
    for (int m = 0; m < 8; ++m) {
        float4 v = *reinterpret_cast<const float4*>(&xx[row0 + m * 16 + q * 4]);
        nxh[m] = -0.5f * fminf(fminf(v.x, v.y), fminf(v.z, v.w));
    }
    // per-iter per-lane thresholds
    float hv[NIT];
#pragma unroll
    for (int it = 0; it < NIT; ++it)
        hv[it] = hc[cw0 + it * WN + r];

    // lane's B base: centre row cw0+r, k-offset q*8; row advances 16/iter
    const u16* bbase = cb + (size_t)(cw0 + r) * FEAT + q * 8;

    // 3-deep B-frag rotation (static %3 under full unroll)
    bf16x8 fr[3][4];
#pragma unroll
    for (int i = 0; i < 2; ++i)
#pragma unroll
        for (int ks = 0; ks < 4; ++ks)
            fr[i][ks] = *reinterpret_cast<const bf16x8*>(bbase + (size_t)i * 16 * FEAT + ks * 32);

    unsigned sus = 0;
#pragma unroll
    for (int it = 0; it < NIT; ++it) {
        if (it + 2 < NIT) {               // issue loads 2 iters ahead
            const u16* p = bbase + (size_t)(it + 2) * 16 * FEAT;
#pragma unroll
            for (int ks = 0; ks < 4; ++ks)
                fr[(it + 2) % 3][ks] = *reinterpret_cast<const bf16x8*>(p + ks * 32);
        }
        f32x4 acc[8];
#pragma unroll
        for (int m = 0; m < 8; ++m)
            acc[m] = f32x4{nxh[m], nxh[m], nxh[m], nxh[m]};
        __builtin_amdgcn_s_setprio(1);
#pragma unroll
        for (int ks = 0; ks < 4; ++ks) {
#pragma unroll
            for (int m = 0; m < 8; ++m)
                acc[m] = __builtin_amdgcn_mfma_f32_16x16x32_bf16(af[m][ks], fr[it % 3][ks], acc[m], 0, 0, 0);
        }
        __builtin_amdgcn_s_setprio(0);

        // screen: max over 32 biased accs vs hv (max3-friendly tree)
        float pm[8];
#pragma unroll
        for (int m = 0; m < 8; ++m)
            pm[m] = fmaxf(fmaxf(acc[m][0], acc[m][1]), fmaxf(acc[m][2], acc[m][3]));
        float v0 = fmaxf(fmaxf(pm[0], pm[1]), fmaxf(pm[2], pm[3]));
        float v1 = fmaxf(fmaxf(pm[4], pm[5]), fmaxf(pm[6], pm[7]));
        float vmax = fmaxf(v0, v1);
        sus |= (vmax > hv[it]) ? (1u << it) : 0u;
    }

    // ---- cold exact path (never taken on this data; correct if taken) ----
    if (__builtin_expect(__any((int)(sus != 0u)), 0)) {
        for (int it = 0; it < NIT; ++it) {
            if (!__any((int)(sus & (1u << it)))) continue;
            const u16* p = bbase + (size_t)it * 16 * FEAT;
            bf16x8 cf[4];
#pragma unroll
            for (int ks = 0; ks < 4; ++ks)
                cf[ks] = *reinterpret_cast<const bf16x8*>(p + ks * 32);
            f32x4 acc[8];
#pragma unroll
            for (int m = 0; m < 8; ++m) acc[m] = f32x4{0.f, 0.f, 0.f, 0.f};
#pragma unroll
            for (int ks = 0; ks < 4; ++ks)
#pragma unroll
                for (int m = 0; m < 8; ++m)
                    acc[m] = __builtin_amdgcn_mfma_f32_16x16x32_bf16(af[m][ks], cf[ks], acc[m], 0, 0, 0);
            const int c = cw0 + it * WN + r;
            const float ccv = cc[c], sv = scale[c];
            const int nd = node_id[c];
#pragma unroll
            for (int m = 0; m < 8; ++m) {
#pragma unroll
                for (int j = 0; j < 4; ++j) {
                    const int row = row0 + m * 16 + q * 4 + j;
                    float sqd = fmaxf(xx[row] + ccv - 2.f * acc[m][j], 0.f);
                    float tt = sqd * sv;
                    if (tt < 96.f) {
                        float phi = __expf(-tt);
                        float* orow = out + (size_t)row * OUT_TYPES;
                        const float* wc = W + nd;
                        for (int n = 0; n < OUT_TYPES; ++n)
                            atomicAdd(&orow[n], phi * wc[(size_t)n * OUT_TYPES]);
                    }
                }
            }
        }
    }
}

// ---------------- launch ------------------------------------------------------
extern "C" void kernel_launch(void* const* d_in, const int* in_sizes, int n_in,
                              void* d_out, int out_size, void* d_ws, size_t ws_size,
                              hipStream_t stream) {
    const float* x       = (const float*)d_in[0];
    const float* centres = (const float*)d_in[1];
    const float* ls      = (const float*)d_in[2];
    const int*   node_id = (const int*)d_in[3];
    const float* W       = (const float*)d_in[4];
    const float* bias    = (const float*)d_in[5];
    float* out = (float*)d_out;

    // ws: xb 1MB | cbb 4MB | cc 64KB | scale 64KB | hc 64KB | xx 16KB
    char* p = (char*)d_ws;
    u16*   xb    = (u16*)p;    p += (size_t)BATCH * FEAT * 2;
    u16*   cbb   = (u16*)p;    p += (size_t)C_TOTAL * FEAT * 2;
    float* cc    = (float*)p;  p += (size_t)C_TOTAL * 4;
    float* scale = (float*)p;  p += (size_t)C_TOTAL * 4;
    float* hc    = (float*)p;  p += (size_t)C_TOTAL * 4;
    float* xx    = (float*)p;  p += (size_t)BATCH * 4;

    hipLaunchKernelGGL(prologue_kernel, dim3(2048 + 256 + 64), dim3(256), 0, stream,
                       x, centres, ls, bias, xb, cbb, cc, scale, hc, xx, out);
    hipLaunchKernelGGL(rbf_kernel, dim3(BATCH / BM * CSPLIT), dim3(256), 0, stream,
                       xb, cbb, hc, cc, scale, node_id, xx, W, out);
}